// Round 3
// baseline (863.352 us; speedup 1.0000x reference)
//
#include <hip/hip_runtime.h>
#include <hip/hip_bf16.h>
#include <stdint.h>

// Problem constants (fixed by the reference).
constexpr int BATCH = 64;
constexpr int T     = 2048;
constexpr int CCH   = 32;
constexpr int OUT_T = 2048;
constexpr int K     = T * CCH;   // 65536
constexpr int N     = OUT_T;     // 2048

// GEMM tiling.
constexpr int TN     = 64;         // n-tile per block
constexpr int NBN    = N / TN;     // 32 n-tiles
constexpr int KSPLIT = 32;         // K-splits (blocks along K)
constexpr int CK     = K / KSPLIT; // 2048 k per block
constexpr int BK     = 32;         // K-step (MFMA K)
constexpr int NS     = CK / BK;    // 64 steps
constexpr int NWG    = NBN * KSPLIT; // 1024 blocks

typedef __attribute__((ext_vector_type(8))) short short8;
typedef __attribute__((ext_vector_type(4))) float f32x4;

// Split fp32 pair -> packed bf16 hi (TRUNCATION, exact) + packed bf16 lo (RNE).
// Bit-identical to rounds 1-2's scalar split (hi trunc; lo RNE via cvt_pk).
__device__ __forceinline__ void split2t(float a, float b, unsigned& hpk, unsigned& lpk) {
  unsigned ua = __float_as_uint(a), ub = __float_as_uint(b);
  hpk = (ua >> 16) | (ub & 0xFFFF0000u);
  float la = a - __uint_as_float(ua & 0xFFFF0000u);
  float lb = b - __uint_as_float(ub & 0xFFFF0000u);
  __hip_bfloat162 l2 = __float22bfloat162_rn(make_float2(la, lb));  // v_cvt_pk_bf16_f32 (RNE)
  __builtin_memcpy(&lpk, &l2, 4);
}

// ---- Kernel 1: precompute X hi/lo bf16 planes (one pass over 16 MB) ----
__global__ __launch_bounds__(256) void xsplit_kernel(
    const float* __restrict__ X, ushort* __restrict__ Xhi, ushort* __restrict__ Xlo) {
  const int i = blockIdx.x * 256 + threadIdx.x;       // float4 index; 1M total
  const float4 v = ((const float4*)X)[i];
  unsigned h01, l01, h23, l23;
  split2t(v.x, v.y, h01, l01);
  split2t(v.z, v.w, h23, l23);
  uint2 hv; hv.x = h01; hv.y = h23;
  uint2 lv; lv.x = l01; lv.y = l23;
  ((uint2*)Xhi)[i] = hv;
  ((uint2*)Xlo)[i] = lv;
}

// ---- Kernel 2: K-split GEMM, A-frags direct from global, B staged via LDS ----
__global__ __launch_bounds__(256) void gemm_split_kernel(
    const ushort* __restrict__ Xhi,   // (64, 65536) bf16
    const ushort* __restrict__ Xlo,
    const float*  __restrict__ W,     // (65536, 2048) fp32
    float* __restrict__ def) {        // (64, 2048) fp32, pre-zeroed
  // XCD-aware bijective swizzle (1024 % 8 == 0): each XCD owns 4 consecutive
  // bk-groups -> 2 MB Xsplit slice L2-resident; W rows fetched by exactly 1 XCD.
  const int bid = blockIdx.x;                     // 0..1023
  const int lb  = (bid & 7) * (NWG / 8) + (bid >> 3);
  const int bn  = lb & (NBN - 1);                 // 0..31
  const int bk  = lb >> 5;                        // 0..31

  const int tid  = threadIdx.x;
  const int lane = tid & 63;
  const int wave = tid >> 6;                      // wave w owns n-frag [16w,16w+16)
  const int r = lane & 15;
  const int g = lane >> 4;

  // LDS: B^T tiles only (64n x 32k), bf16 hi/lo, double-buffered. 20 KB total.
  __shared__ ushort Bhi[2][64][40];   // stride 40 ushort = 80 B (16B-aligned rows)
  __shared__ ushort Blo[2][64][40];

  f32x4 acc[4] = {};                  // 4 m-frags x 16 n cols
  const int kbase = bk * CK;

  // Per-lane A-frag byte offsets into Xhi/Xlo: row = mf*16+r, k = k0 + 8g.
  unsigned aOff[4];
#pragma unroll
  for (int mf = 0; mf < 4; ++mf)
    aOff[mf] = (unsigned)((mf * 16 + r) * (K * 2) + (kbase + 8 * g) * 2);

  auto issueA = [&](short8 (&ah)[4], short8 (&al)[4]) {
#pragma unroll
    for (int mf = 0; mf < 4; ++mf) {
      ah[mf] = *(const short8*)((const char*)Xhi + aOff[mf]);
      al[mf] = *(const short8*)((const char*)Xlo + aOff[mf]);
    }
#pragma unroll
    for (int mf = 0; mf < 4; ++mf) aOff[mf] += BK * 2;   // advance one K-step
  };

  auto issueB = [&](int ks, float (&bb)[8]) {
    const int k0 = kbase + ks * BK;
#pragma unroll
    for (int it = 0; it < 2; ++it) {
      int flat = it * 256 + tid;      // 0..511
      int n  = flat & 63;             // wave reads 256B contiguous per k-row
      int kq = flat >> 6;             // 0..7
      const float* wp = &W[(size_t)(k0 + kq * 4) * N + bn * TN + n];
#pragma unroll
      for (int j = 0; j < 4; ++j) bb[it * 4 + j] = wp[(size_t)j * N];
    }
  };

  auto stageB = [&](int buf, float (&bb)[8]) {
#pragma unroll
    for (int it = 0; it < 2; ++it) {
      int flat = it * 256 + tid;
      int n  = flat & 63;
      int kq = flat >> 6;
      unsigned h01, l01, h23, l23;
      split2t(bb[it * 4 + 0], bb[it * 4 + 1], h01, l01);
      split2t(bb[it * 4 + 2], bb[it * 4 + 3], h23, l23);
      uint2 hv; hv.x = h01; hv.y = h23;
      uint2 lv; lv.x = l01; lv.y = l23;
      *(uint2*)&Bhi[buf][n][kq * 4] = hv;
      *(uint2*)&Blo[buf][n][kq * 4] = lv;
    }
  };

  auto mfma_step = [&](int buf, short8 (&ah)[4], short8 (&al)[4]) {
    short8 bh = *(const short8*)&Bhi[buf][wave * 16 + r][g * 8];
    short8 bl = *(const short8*)&Blo[buf][wave * 16 + r][g * 8];
#pragma unroll
    for (int mf = 0; mf < 4; ++mf) {
      acc[mf] = __builtin_amdgcn_mfma_f32_16x16x32_bf16(ah[mf], bh, acc[mf], 0, 0, 0);
      acc[mf] = __builtin_amdgcn_mfma_f32_16x16x32_bf16(ah[mf], bl, acc[mf], 0, 0, 0);
      acc[mf] = __builtin_amdgcn_mfma_f32_16x16x32_bf16(al[mf], bh, acc[mf], 0, 0, 0);
    }
  };

  short8 aCh[4], aCl[4], aNh[4], aNl[4];
  float bReg0[8], bReg1[8];

  // Prologue: LDS[0] = B(0), bReg1 = W(1) raw, aC = A(0).
  issueB(0, bReg0);
  issueB(1, bReg1);
  issueA(aCh, aCl);                    // A(0); offsets now at step 1
  stageB(0, bReg0);                    // waits on bReg0
  __syncthreads();

  for (int t = 0; t < NS; t += 2) {
    // even step t (buf 0): aC = A(t), LDS[0] = B(t), bReg1 = W(t+1)
    issueA(aNh, aNl);                              // A(t+1)
    if (t + 2 < NS) issueB(t + 2, bReg0);          // W(t+2)
    mfma_step(0, aCh, aCl);
    stageB(1, bReg1);                              // B(t+1) -> LDS[1]
    __syncthreads();

    // odd step t+1 (buf 1): aN = A(t+1), LDS[1] = B(t+1), bReg0 = W(t+2)
    if (t + 2 < NS) issueA(aCh, aCl);              // A(t+2)
    if (t + 3 < NS) issueB(t + 3, bReg1);          // W(t+3)
    mfma_step(1, aNh, aNl);
    if (t + 2 < NS) stageB(0, bReg0);              // B(t+2) -> LDS[0]
    __syncthreads();
  }

  // Epilogue: atomically accumulate K-split partials.
  // C/D layout: col = lane&15 (n), row = 4*(lane>>4) + reg (m within 16-frag).
  const int ncol = bn * TN + wave * 16 + r;
#pragma unroll
  for (int mf = 0; mf < 4; ++mf) {
    const int mbase = mf * 16 + g * 4;
#pragma unroll
    for (int q = 0; q < 4; ++q) {
      atomicAdd(&def[(size_t)(mbase + q) * N + ncol], acc[mf][q]);
    }
  }
}

// ---- Kernel 3: resample (unchanged, passed) ----
__global__ __launch_bounds__(256) void resample_kernel(
    const float* __restrict__ X,       // (64, 2048, 32)
    const float* __restrict__ def,     // (64, 2048)
    const float* __restrict__ b_loc,   // (2048,)
    float* __restrict__ out) {         // (64, 2048, 32)
  const int tid = blockIdx.x * 256 + threadIdx.x;  // 64*2048*8 total
  const int c4 = tid & 7;
  const int o  = (tid >> 3) & (OUT_T - 1);
  const int b  = tid >> 14;

  const float x = (float)o + def[b * OUT_T + o] + b_loc[o];
  const float xf = floorf(x);
  const int x0 = (int)xf;
  const int x1 = x0 + 1;
  const int x0c = min(max(x0, 0), T - 1);
  const int x1c = min(max(x1, 0), T - 1);
  const float w0 = (float)x1c - x;    // weights use CLIPPED coords (faithful)
  const float w1 = x - (float)x0c;

  const float4 v0 = *(const float4*)&X[((size_t)b * T + x0c) * CCH + c4 * 4];
  const float4 v1 = *(const float4*)&X[((size_t)b * T + x1c) * CCH + c4 * 4];
  float4 res;
  res.x = w0 * v0.x + w1 * v1.x;
  res.y = w0 * v0.y + w1 * v1.y;
  res.z = w0 * v0.z + w1 * v1.z;
  res.w = w0 * v0.w + w1 * v1.w;
  *(float4*)&out[((size_t)b * OUT_T + o) * CCH + c4 * 4] = res;
}

extern "C" void kernel_launch(void* const* d_in, const int* in_sizes, int n_in,
                              void* d_out, int out_size, void* d_ws, size_t ws_size,
                              hipStream_t stream) {
  const float* X     = (const float*)d_in[0];
  const float* W     = (const float*)d_in[1];
  const float* b_loc = (const float*)d_in[2];
  float* out = (float*)d_out;

  // d_ws layout: def (512 KB) @0, Xhi (8 MB) @1MB, Xlo (8 MB) @9MB.
  float*  def = (float*)d_ws;
  ushort* Xhi = (ushort*)((char*)d_ws + (1u << 20));
  ushort* Xlo = (ushort*)((char*)d_ws + (1u << 20) + (size_t)BATCH * K * 2);

  hipMemsetAsync(def, 0, (size_t)BATCH * N * sizeof(float), stream);

  xsplit_kernel<<<(BATCH * K / 4) / 256, 256, 0, stream>>>(X, Xhi, Xlo);

  gemm_split_kernel<<<NWG, 256, 0, stream>>>(Xhi, Xlo, W, def);

  resample_kernel<<<(BATCH * OUT_T * 8) / 256, 256, 0, stream>>>(X, def, b_loc, out);
}